// Round 9
// baseline (282.953 us; speedup 1.0000x reference)
//
#include <hip/hip_runtime.h>

#define DD    48
#define SP    (48*48*48)      // 110592 voxels
#define CIN   16
#define COUT  32
#define KK    9
#define NG    8               // groupnorm groups
#define EPSV  1e-5f

// ---------------------------------------------------------------------------
// Kernel 0: zero the (padded) stats buffer: 256 floats, one counter per 64B
// ---------------------------------------------------------------------------
__global__ __launch_bounds__(256) void k_zero(float* __restrict__ stats) {
    stats[threadIdx.x] = 0.0f;
}

// ---------------------------------------------------------------------------
// Kernel 0b: transpose x [ci][v] -> xt [v][ci]  (one voxel's 16 ci = 64B line)
// ---------------------------------------------------------------------------
__global__ __launch_bounds__(256) void k_xt(const float* __restrict__ x,
                                            float* __restrict__ xt) {
    int t = threadIdx.x;
    int vb = t >> 2, c = t & 3;
    int v = blockIdx.x * 64 + vb;
    float4 o;
    o.x = x[(4 * c + 0) * SP + v];
    o.y = x[(4 * c + 1) * SP + v];
    o.z = x[(4 * c + 2) * SP + v];
    o.w = x[(4 * c + 3) * SP + v];
    *reinterpret_cast<float4*>(xt + v * 16 + 4 * c) = o;
}

// ---------------------------------------------------------------------------
// FUSED kernel: offset conv 3x3x3 (16->18) + BN + tanh  [all in registers]
//             -> snake cumsum -> bilinear(z,y) sample -> (1,1,K) conv (16->32)
//             -> pre-GN out + stats.
// Valid because off[k] is consumed only at the producing voxel (cumsum is
// channel-wise at fixed spatial pos). Block 256 = 64 voxels x 4 ci-chunks;
// conv partials chunk-reduced with shfl_xor(1,2) -> every lane holds all 18
// offsets; then phase 2 is the proven R8 k_snake body.
// LDS: conv w 31.1 KB ([tap][c][co18][ci4], 72-dw chunk stride, bank offsets
// 0/8/16/24 -> conflict-free b128 broadcast) + snake w 19 KB (132-dw stride,
// offsets 0/4/8/12 -> conflict-free) = ~50 KB -> 3 blocks/CU.
// NO min-waves clause (R3 lesson: forced VGPR cap -> 381 MB spill traffic).
// ---------------------------------------------------------------------------
__global__ __launch_bounds__(256) void k_fused(
    const float* __restrict__ xt,  const float* __restrict__ ow,
    const float* __restrict__ ob,  const float* __restrict__ bng,
    const float* __restrict__ bnb, const float* __restrict__ bnm,
    const float* __restrict__ bnv, const float* __restrict__ dw,
    const float* __restrict__ db,  float* __restrict__ pre,
    float* __restrict__ stats)
{
    __shared__ float cw[27 * 4 * 72];    // conv weights, 31104 B
    __shared__ float wl[KK * 4 * 132];   // snake weights, 19008 B
    __shared__ float bnsc[18], bnsh[18];
    __shared__ float lstat[16];

    for (int i = threadIdx.x; i < 27 * CIN * 18; i += 256) {
        int ch = i % 18; int r = i / 18; int ci = r % CIN; int tap = r / CIN;
        int c = ci >> 2, j = ci & 3;
        cw[(tap * 4 + c) * 72 + ch * 4 + j] = ow[(ch * CIN + ci) * 27 + tap];
    }
    for (int i = threadIdx.x; i < KK * CIN * COUT; i += 256) {
        int co = i % COUT; int r = i / COUT; int ci = r % CIN; int k = r / CIN;
        int c = ci >> 2, j = ci & 3;
        wl[(k * 4 + c) * 132 + co * 4 + j] = dw[(co * CIN + ci) * KK + k];
    }
    if (threadIdx.x < 18) {
        int ch = threadIdx.x;
        float sc = bng[ch] * rsqrtf(bnv[ch] + EPSV);
        bnsc[ch] = sc;
        bnsh[ch] = (ob[ch] - bnm[ch]) * sc + bnb[ch];
    }
    if (threadIdx.x < 16) lstat[threadIdx.x] = 0.0f;
    __syncthreads();

    // XCD-aware swizzle (1728 % 8 == 0 -> bijective)
    const int nwg = SP / 64;                 // 1728
    int bid = (int)blockIdx.x;
    bid = (bid & 7) * (nwg >> 3) + (bid >> 3);

    const int t  = threadIdx.x;
    const int c  = t & 3;                    // ci chunk (ci = 4c..4c+3)
    const int vb = t >> 2;                   // voxel in block 0..63
    const int v  = bid * 64 + vb;
    const int h = v % DD, w = (v / DD) % DD, d = v / (DD * DD);

    const float* xc = xt + 4 * c;

    // ---- phase 1: offset conv (this chunk's 4 ci), acc over 18 channels ----
    float a18[18];
#pragma unroll
    for (int co = 0; co < 18; ++co) a18[co] = 0.0f;

#pragma unroll
    for (int kd = 0; kd < 3; ++kd) {
        int z = d + kd - 1; bool okz = (unsigned)z < (unsigned)DD;
#pragma unroll
        for (int kw = 0; kw < 3; ++kw) {
            int yy = w + kw - 1; bool oky = (unsigned)yy < (unsigned)DD;
#pragma unroll
            for (int kh = 0; kh < 3; ++kh) {
                int xx = h + kh - 1;
                if (okz && oky && (unsigned)xx < (unsigned)DD) {
                    int tap = (kd * 3 + kw) * 3 + kh;
                    float4 xv = *reinterpret_cast<const float4*>(
                        xc + ((z * DD + yy) * DD + xx) * 16);
                    const float4* wrow = reinterpret_cast<const float4*>(
                        &cw[(tap * 4 + c) * 72]);
#pragma unroll
                    for (int co = 0; co < 18; ++co) {
                        float4 w4 = wrow[co];
                        a18[co] += w4.x * xv.x + w4.y * xv.y
                                 + w4.z * xv.z + w4.w * xv.w;
                    }
                }
            }
        }
    }

    // chunk-reduce conv partials -> every lane holds full conv sums
#pragma unroll
    for (int co = 0; co < 18; ++co) {
        a18[co] += __shfl_xor(a18[co], 1);
        a18[co] += __shfl_xor(a18[co], 2);
        // BN(eval) + tanh, in place: a18 = offset values
        a18[co] = tanhf(a18[co] * bnsc[co] + bnsh[co]);
    }

    // ---- phase 2: snake sample + (1,1,K) conv (R8 k_snake body) ----
    float acc[COUT];
#pragma unroll
    for (int co = 0; co < COUT; ++co) acc[co] = 0.0f;

    // One tap: z = d+czv, y = w+cyv, x-col = h+k-4 (exact int -> x-weight is
    // 1 unless clipped col hits DD-1, where it's exactly 0 -> skip).
    auto process = [&](int k, float czv, float cyv) {
        int xcol = h + k - 4;
        if (xcol >= DD - 1) return;
        if (xcol < 0) xcol = 0;

        float zf = fminf(fmaxf((float)d + czv, 0.0f), 47.0f);
        float yf = fminf(fmaxf((float)w + cyv, 0.0f), 47.0f);
        int z0 = (int)zf, y0 = (int)yf;
        int z1 = min(z0 + 1, 47), y1 = min(y0 + 1, 47);
        float wz1 = zf - (float)z0, wz0 = (float)z1 - zf;
        float wy1 = yf - (float)y0, wy0 = (float)y1 - yf;
        float w00 = wz0 * wy0, w01 = wz0 * wy1, w10 = wz1 * wy0, w11 = wz1 * wy1;

        const float* base = xt + 4 * c;
        float s0, s1, s2, s3;
        {
            const float4 A = *reinterpret_cast<const float4*>(base + ((z0 * DD + y0) * DD + xcol) * 16);
            const float4 B = *reinterpret_cast<const float4*>(base + ((z0 * DD + y1) * DD + xcol) * 16);
            s0 = w00 * A.x + w01 * B.x;
            s1 = w00 * A.y + w01 * B.y;
            s2 = w00 * A.z + w01 * B.z;
            s3 = w00 * A.w + w01 * B.w;
        }
        {
            const float4 C = *reinterpret_cast<const float4*>(base + ((z1 * DD + y0) * DD + xcol) * 16);
            const float4 E = *reinterpret_cast<const float4*>(base + ((z1 * DD + y1) * DD + xcol) * 16);
            s0 += w10 * C.x + w11 * E.x;
            s1 += w10 * C.y + w11 * E.y;
            s2 += w10 * C.z + w11 * E.z;
            s3 += w10 * C.w + w11 * E.w;
        }

        const float4* wrow = reinterpret_cast<const float4*>(&wl[(k * 4 + c) * 132]);
#pragma unroll
        for (int co = 0; co < COUT; ++co) {
            float4 w4 = wrow[co];
            acc[co] += w4.x * s0 + w4.y * s1 + w4.z * s2 + w4.w * s3;
        }
    };

    // Walk k outward from center: incremental snake cumsum (static indices).
    process(4, 0.0f, 0.0f);
    {
        float rz = 0.0f, ry = 0.0f;
#pragma unroll
        for (int k = 3; k >= 0; --k) {
            rz += a18[k];
            ry += a18[KK + k];
            process(k, rz, ry);
        }
    }
    {
        float rz = 0.0f, ry = 0.0f;
#pragma unroll
        for (int k = 5; k < KK; ++k) {
            rz += a18[k];
            ry += a18[KK + k];
            process(k, rz, ry);
        }
    }

    // Reduce the 4 ci-chunk partials (lane bits 0..1) -> all lanes full acc
#pragma unroll
    for (int co = 0; co < COUT; ++co) {
        acc[co] += __shfl_xor(acc[co], 1);
        acc[co] += __shfl_xor(acc[co], 2);
        acc[co] += db[co];
    }

    // Store: lane chunk cc writes co = cc*8 .. cc*8+7 (static indices per arm)
#pragma unroll
    for (int cc = 0; cc < 4; ++cc) {
        if (c == cc) {
#pragma unroll
            for (int j = 0; j < 8; ++j)
                pre[(cc * 8 + j) * SP + v] = acc[cc * 8 + j];
        }
    }

    // GN stats: per-lane group sums; xor over lane bits 2..5 sums the 16
    // voxels within each chunk-class (each voxel counted exactly once).
#pragma unroll
    for (int g = 0; g < NG; ++g) {
        float a0 = acc[4*g], a1 = acc[4*g+1], a2 = acc[4*g+2], a3 = acc[4*g+3];
        float s  = a0 + a1 + a2 + a3;
        float ss = a0*a0 + a1*a1 + a2*a2 + a3*a3;
#pragma unroll
        for (int o = 4; o <= 32; o <<= 1) {
            s  += __shfl_xor(s,  o);
            ss += __shfl_xor(ss, o);
        }
        if ((t & 63) == 0) {
            atomicAdd(&lstat[g],      s);
            atomicAdd(&lstat[NG + g], ss);
        }
    }
    __syncthreads();
    if (t < 16) atomicAdd(&stats[t * 16], lstat[t]);   // padded: 1 counter/64B
}

// ---------------------------------------------------------------------------
// Kernel 3: GroupNorm finalize + affine + ReLU, IN-PLACE on d_out (float4)
// ---------------------------------------------------------------------------
__global__ __launch_bounds__(256) void k_gn(
    float* __restrict__ buf, const float* __restrict__ stats,
    const float* __restrict__ gamma, const float* __restrict__ beta)
{
    int idx  = blockIdx.x * 256 + threadIdx.x;   // float4 index
    int base = idx * 4;
    int ch = base / SP, g = ch >> 2;

    const float inv_n = 1.0f / (4.0f * (float)SP);
    float mean = stats[g * 16] * inv_n;
    float var  = stats[(NG + g) * 16] * inv_n - mean * mean;
    float rs   = rsqrtf(var + EPSV);
    float ga   = gamma[ch] * rs;
    float be   = beta[ch] - mean * ga;

    float4 p = *reinterpret_cast<const float4*>(buf + base);
    float4 o;
    o.x = fmaxf(p.x * ga + be, 0.0f);
    o.y = fmaxf(p.y * ga + be, 0.0f);
    o.z = fmaxf(p.z * ga + be, 0.0f);
    o.w = fmaxf(p.w * ga + be, 0.0f);
    *reinterpret_cast<float4*>(buf + base) = o;
}

// ---------------------------------------------------------------------------
extern "C" void kernel_launch(void* const* d_in, const int* in_sizes, int n_in,
                              void* d_out, int out_size, void* d_ws, size_t ws_size,
                              hipStream_t stream)
{
    const float* x   = (const float*)d_in[0];
    const float* ow  = (const float*)d_in[1];
    const float* ob  = (const float*)d_in[2];
    const float* bng = (const float*)d_in[3];
    const float* bnb = (const float*)d_in[4];
    const float* bnm = (const float*)d_in[5];
    const float* bnv = (const float*)d_in[6];
    const float* dw  = (const float*)d_in[7];
    const float* db  = (const float*)d_in[8];
    const float* gng = (const float*)d_in[9];
    const float* gnb = (const float*)d_in[10];
    float* out = (float*)d_out;

    float* xt    = (float*)d_ws;             // 16 * SP floats (7.08 MB)
    float* stats = xt + CIN * SP;            // 256 floats (padded counters)

    k_zero <<<1, 256, 0, stream>>>(stats);
    k_xt   <<<SP / 64, 256, 0, stream>>>(x, xt);
    k_fused<<<SP / 64, 256, 0, stream>>>(xt, ow, ob, bng, bnb, bnm, bnv,
                                         dw, db, out, stats);
    k_gn   <<<(COUT * SP / 4) / 256, 256, 0, stream>>>(out, stats, gng, gnb);
}

// Round 16
// 222.973 us; speedup vs baseline: 1.2690x; 1.2690x over previous
//
#include <hip/hip_runtime.h>

#define DD    48
#define SP    (48*48*48)      // 110592 voxels
#define CIN   16
#define COUT  32
#define KK    9
#define NG    8               // groupnorm groups
#define EPSV  1e-5f

// ---------------------------------------------------------------------------
// Kernel 0: transpose x [ci][v] -> xt [v][ci] (one voxel's 16 ci = 64B line).
// Block 0 also zeros the padded stats buffer (stream order guarantees
// completion before k_snake's atomics).
// ---------------------------------------------------------------------------
__global__ __launch_bounds__(256) void k_xt(const float* __restrict__ x,
                                            float* __restrict__ xt,
                                            float* __restrict__ stats) {
    int t = threadIdx.x;
    int vb = t >> 2, c = t & 3;
    int v = blockIdx.x * 64 + vb;
    float4 o;
    o.x = x[(4 * c + 0) * SP + v];
    o.y = x[(4 * c + 1) * SP + v];
    o.z = x[(4 * c + 2) * SP + v];
    o.w = x[(4 * c + 3) * SP + v];
    *reinterpret_cast<float4*>(xt + v * 16 + 4 * c) = o;
    if (blockIdx.x == 0) stats[t] = 0.0f;
}

// ---------------------------------------------------------------------------
// Kernel 1: offset conv 3x3x3 (16 -> ALL 18 ch in one pass) + BN(eval) + tanh.
// Block 256 = 64 voxels x 4 ci-chunks; chunk partials reduced shfl_xor(1,2).
// off layout: [ch][v]  (ch 0..8 = z-offsets, 9..17 = y-offsets)
// ---------------------------------------------------------------------------
__global__ __launch_bounds__(256) void k_off18(
    const float* __restrict__ xt,  const float* __restrict__ ow,
    const float* __restrict__ ob,  const float* __restrict__ bng,
    const float* __restrict__ bnb, const float* __restrict__ bnm,
    const float* __restrict__ bnv, float* __restrict__ off)
{
    __shared__ float cw[27 * 4 * 72];    // [tap][c][ch18][ci4], 31104 B
    __shared__ float bnsc[18], bnsh[18];

    for (int i = threadIdx.x; i < 27 * CIN * 18; i += 256) {
        int ch = i % 18; int r = i / 18; int ci = r % CIN; int tap = r / CIN;
        int c = ci >> 2, j = ci & 3;
        cw[(tap * 4 + c) * 72 + ch * 4 + j] = ow[(ch * CIN + ci) * 27 + tap];
    }
    if (threadIdx.x < 18) {
        int ch = threadIdx.x;
        float sc = bng[ch] * rsqrtf(bnv[ch] + EPSV);
        bnsc[ch] = sc;
        bnsh[ch] = (ob[ch] - bnm[ch]) * sc + bnb[ch];
    }
    __syncthreads();

    // XCD-aware swizzle (1728 % 8 == 0 -> bijective)
    const int nwg = SP / 64;
    int bid = (int)blockIdx.x;
    bid = (bid & 7) * (nwg >> 3) + (bid >> 3);

    const int t  = threadIdx.x;
    const int c  = t & 3;
    const int vb = t >> 2;
    const int v  = bid * 64 + vb;
    const int h = v % DD, w = (v / DD) % DD, d = v / (DD * DD);

    const float* xc = xt + 4 * c;

    float a18[18];
#pragma unroll
    for (int ch = 0; ch < 18; ++ch) a18[ch] = 0.0f;

#pragma unroll
    for (int kd = 0; kd < 3; ++kd) {
        int z = d + kd - 1; bool okz = (unsigned)z < (unsigned)DD;
#pragma unroll
        for (int kw = 0; kw < 3; ++kw) {
            int yy = w + kw - 1; bool oky = (unsigned)yy < (unsigned)DD;
#pragma unroll
            for (int kh = 0; kh < 3; ++kh) {
                int xx = h + kh - 1;
                if (okz && oky && (unsigned)xx < (unsigned)DD) {
                    int tap = (kd * 3 + kw) * 3 + kh;
                    float4 xv = *reinterpret_cast<const float4*>(
                        xc + ((z * DD + yy) * DD + xx) * 16);
                    const float4* wrow = reinterpret_cast<const float4*>(
                        &cw[(tap * 4 + c) * 72]);
#pragma unroll
                    for (int ch = 0; ch < 18; ++ch) {
                        float4 w4 = wrow[ch];
                        a18[ch] += w4.x * xv.x + w4.y * xv.y
                                 + w4.z * xv.z + w4.w * xv.w;
                    }
                }
            }
        }
    }

#pragma unroll
    for (int ch = 0; ch < 18; ++ch) {
        a18[ch] += __shfl_xor(a18[ch], 1);
        a18[ch] += __shfl_xor(a18[ch], 2);
        a18[ch] = tanhf(a18[ch] * bnsc[ch] + bnsh[ch]);
    }

    // static-index write arms (runtime-indexed reg arrays -> scratch, rule #20)
#pragma unroll
    for (int cc = 0; cc < 4; ++cc) {
        if (c == cc) {
#pragma unroll
            for (int j = 0; j < 4; ++j)
                off[(cc * 4 + j) * SP + v] = a18[cc * 4 + j];
        }
    }
    if (c == 0) off[16 * SP + v] = a18[16];
    if (c == 1) off[17 * SP + v] = a18[17];
}

// ---------------------------------------------------------------------------
// Kernel 2: snake sample + fused (1,1,K)-stride-K conv (16->32) + GN stats.
// Coords for ALL 9 taps precomputed upfront; dead taps = weight-0 (no
// divergent skip); gather->FMA is a fully-unrolled 2-deep software pipeline.
// ---------------------------------------------------------------------------
__global__ __launch_bounds__(256) void k_snake(
    const float* __restrict__ xt,  const float* __restrict__ off,
    const float* __restrict__ dw,  const float* __restrict__ db,
    float* __restrict__ pre,       float* __restrict__ stats)
{
    // wl[(k*4 + c)*132 + co*4 + j] = dw[co][ci=4c+j][k]; 19 KB
    // chunk bank offsets 0/4/8/12 -> conflict-free b128 broadcast
    __shared__ float wl[KK * 4 * 132];
    __shared__ float lstat[16];
    for (int i = threadIdx.x; i < KK * CIN * COUT; i += 256) {
        int co = i % COUT; int r = i / COUT; int ci = r % CIN; int k = r / CIN;
        int c = ci >> 2, j = ci & 3;
        wl[(k * 4 + c) * 132 + co * 4 + j] = dw[(co * CIN + ci) * KK + k];
    }
    if (threadIdx.x < 16) lstat[threadIdx.x] = 0.0f;
    __syncthreads();

    // XCD-aware swizzle (1728 % 8 == 0 -> bijective)
    const int nwg = SP / 64;
    int bid = (int)blockIdx.x;
    bid = (bid & 7) * (nwg >> 3) + (bid >> 3);

    const int t  = threadIdx.x;
    const int c  = t & 3;                    // ci chunk (ci = 4c..4c+3)
    const int vb = t >> 2;                   // voxel in block 0..63
    const int v  = bid * 64 + vb;
    const int h = v % DD, w = (v / DD) % DD, d = v / (DD * DD);

    // ---- offsets + snake cumsum (all static-indexed, fully unrolled) ----
    float cz[9], cy[9];
    cz[4] = 0.0f; cy[4] = 0.0f;
    {
        float rz = 0.0f, ry = 0.0f;
#pragma unroll
        for (int k = 3; k >= 0; --k) {
            rz += off[k * SP + v];        cz[k] = rz;
            ry += off[(KK + k) * SP + v]; cy[k] = ry;
        }
    }
    {
        float rz = 0.0f, ry = 0.0f;
#pragma unroll
        for (int k = 5; k < KK; ++k) {
            rz += off[k * SP + v];        cz[k] = rz;
            ry += off[(KK + k) * SP + v]; cy[k] = ry;
        }
    }

    // ---- per-tap bilinear weights + corner addresses (upfront) ----
    // x-col = h+k-4 exact int: weight 1, or exactly 0 if clipped col hits 47.
    float w00[9], w01[9], w10[9], w11[9];
    int   b00[9], b01[9], b10[9], b11[9];
#pragma unroll
    for (int k = 0; k < 9; ++k) {
        int xcol = h + k - 4;
        float m = (xcol >= DD - 1) ? 0.0f : 1.0f;
        if (xcol < 0 || xcol >= DD - 1) xcol = 0;   // safe addr; weight covers it
        float zf = fminf(fmaxf((float)d + cz[k], 0.0f), 47.0f);
        float yf = fminf(fmaxf((float)w + cy[k], 0.0f), 47.0f);
        int z0 = (int)zf, y0 = (int)yf;
        int z1 = min(z0 + 1, 47), y1 = min(y0 + 1, 47);
        float wz1 = zf - (float)z0, wz0 = (float)z1 - zf;
        float wy1 = yf - (float)y0, wy0 = (float)y1 - yf;
        w00[k] = wz0 * wy0 * m; w01[k] = wz0 * wy1 * m;
        w10[k] = wz1 * wy0 * m; w11[k] = wz1 * wy1 * m;
        b00[k] = ((z0 * DD + y0) * DD + xcol) * 16;
        b01[k] = ((z0 * DD + y1) * DD + xcol) * 16;
        b10[k] = ((z1 * DD + y0) * DD + xcol) * 16;
        b11[k] = ((z1 * DD + y1) * DD + xcol) * 16;
    }

    // ---- 2-deep software-pipelined gather + FMA ----
    // NOTE: pasted names parenthesized ((P##0).x) — bare P##0.x lexes "0.x"
    // as one pp-number and the paste forms an invalid token (R14 compile fail).
    const float* base = xt + 4 * c;
    float acc[COUT];
#pragma unroll
    for (int co = 0; co < COUT; ++co) acc[co] = 0.0f;

    float4 A0, A1, A2, A3, B0, B1, B2, B3;

#define LOADP(P, k)                                                        \
    (P##0) = *reinterpret_cast<const float4*>(base + b00[k]);              \
    (P##1) = *reinterpret_cast<const float4*>(base + b01[k]);              \
    (P##2) = *reinterpret_cast<const float4*>(base + b10[k]);              \
    (P##3) = *reinterpret_cast<const float4*>(base + b11[k]);

#define FMAP(P, k)                                                         \
    {                                                                      \
        float s0 = w00[k]*(P##0).x + w01[k]*(P##1).x + w10[k]*(P##2).x + w11[k]*(P##3).x; \
        float s1 = w00[k]*(P##0).y + w01[k]*(P##1).y + w10[k]*(P##2).y + w11[k]*(P##3).y; \
        float s2 = w00[k]*(P##0).z + w01[k]*(P##1).z + w10[k]*(P##2).z + w11[k]*(P##3).z; \
        float s3 = w00[k]*(P##0).w + w01[k]*(P##1).w + w10[k]*(P##2).w + w11[k]*(P##3).w; \
        const float4* wrow = reinterpret_cast<const float4*>(&wl[((k)*4 + c) * 132]); \
        _Pragma("unroll")                                                  \
        for (int co = 0; co < COUT; ++co) {                                \
            float4 w4 = wrow[co];                                          \
            acc[co] += w4.x * s0 + w4.y * s1 + w4.z * s2 + w4.w * s3;      \
        }                                                                  \
    }

    LOADP(A, 0)
    LOADP(B, 1) FMAP(A, 0)
    LOADP(A, 2) FMAP(B, 1)
    LOADP(B, 3) FMAP(A, 2)
    LOADP(A, 4) FMAP(B, 3)
    LOADP(B, 5) FMAP(A, 4)
    LOADP(A, 6) FMAP(B, 5)
    LOADP(B, 7) FMAP(A, 6)
    LOADP(A, 8) FMAP(B, 7)
    FMAP(A, 8)
#undef LOADP
#undef FMAP

    // Reduce the 4 ci-chunk partials -> all lanes hold full acc
#pragma unroll
    for (int co = 0; co < COUT; ++co) {
        acc[co] += __shfl_xor(acc[co], 1);
        acc[co] += __shfl_xor(acc[co], 2);
        acc[co] += db[co];
    }

    // Store: lane chunk cc writes co = cc*8 .. cc*8+7 (static indices per arm)
#pragma unroll
    for (int cc = 0; cc < 4; ++cc) {
        if (c == cc) {
#pragma unroll
            for (int j = 0; j < 8; ++j)
                pre[(cc * 8 + j) * SP + v] = acc[cc * 8 + j];
        }
    }

    // GN stats: per-lane group sums; xor over lane bits 2..5 sums the 16
    // voxels within each chunk-class (each voxel counted exactly once).
#pragma unroll
    for (int g = 0; g < NG; ++g) {
        float a0 = acc[4*g], a1 = acc[4*g+1], a2 = acc[4*g+2], a3 = acc[4*g+3];
        float s  = a0 + a1 + a2 + a3;
        float ss = a0*a0 + a1*a1 + a2*a2 + a3*a3;
#pragma unroll
        for (int o = 4; o <= 32; o <<= 1) {
            s  += __shfl_xor(s,  o);
            ss += __shfl_xor(ss, o);
        }
        if ((t & 63) == 0) {
            atomicAdd(&lstat[g],      s);
            atomicAdd(&lstat[NG + g], ss);
        }
    }
    __syncthreads();
    if (t < 16) atomicAdd(&stats[t * 16], lstat[t]);   // padded: 1 counter/64B
}

// ---------------------------------------------------------------------------
// Kernel 3: GroupNorm finalize + affine + ReLU, IN-PLACE on d_out (float4)
// ---------------------------------------------------------------------------
__global__ __launch_bounds__(256) void k_gn(
    float* __restrict__ buf, const float* __restrict__ stats,
    const float* __restrict__ gamma, const float* __restrict__ beta)
{
    int idx  = blockIdx.x * 256 + threadIdx.x;   // float4 index
    int base = idx * 4;
    int ch = base / SP, g = ch >> 2;

    const float inv_n = 1.0f / (4.0f * (float)SP);
    float mean = stats[g * 16] * inv_n;
    float var  = stats[(NG + g) * 16] * inv_n - mean * mean;
    float rs   = rsqrtf(var + EPSV);
    float ga   = gamma[ch] * rs;
    float be   = beta[ch] - mean * ga;

    float4 p = *reinterpret_cast<const float4*>(buf + base);
    float4 o;
    o.x = fmaxf(p.x * ga + be, 0.0f);
    o.y = fmaxf(p.y * ga + be, 0.0f);
    o.z = fmaxf(p.z * ga + be, 0.0f);
    o.w = fmaxf(p.w * ga + be, 0.0f);
    *reinterpret_cast<float4*>(buf + base) = o;
}

// ---------------------------------------------------------------------------
extern "C" void kernel_launch(void* const* d_in, const int* in_sizes, int n_in,
                              void* d_out, int out_size, void* d_ws, size_t ws_size,
                              hipStream_t stream)
{
    const float* x   = (const float*)d_in[0];
    const float* ow  = (const float*)d_in[1];
    const float* ob  = (const float*)d_in[2];
    const float* bng = (const float*)d_in[3];
    const float* bnb = (const float*)d_in[4];
    const float* bnm = (const float*)d_in[5];
    const float* bnv = (const float*)d_in[6];
    const float* dw  = (const float*)d_in[7];
    const float* db  = (const float*)d_in[8];
    const float* gng = (const float*)d_in[9];
    const float* gnb = (const float*)d_in[10];
    float* out = (float*)d_out;

    float* xt    = (float*)d_ws;             // 16 * SP floats (7.08 MB)
    float* stats = xt + CIN * SP;            // 256 floats (padded counters)
    float* off   = stats + 256;              // 18 * SP floats (7.96 MB)

    k_xt   <<<SP / 64, 256, 0, stream>>>(x, xt, stats);
    k_off18<<<SP / 64, 256, 0, stream>>>(xt, ow, ob, bng, bnb, bnm, bnv, off);
    k_snake<<<SP / 64, 256, 0, stream>>>(xt, off, dw, db, out, stats);
    k_gn   <<<(COUT * SP / 4) / 256, 256, 0, stream>>>(out, stats, gng, gnb);
}